// Round 8
// baseline (2671.836 us; speedup 1.0000x reference)
//
#include <hip/hip_runtime.h>

// GRU classifier: x[256,512,128] -> GRU(H=512) -> head -> out[256,1000]
// R5: 128 persistent blocks (16 groups x 8 blocks, 64 cols/block), weights in
// VGPRs. Chain-latency-focused: h exchanged in MFMA-fragment layout via IC
// (relaxed agent atomics) loaded DIRECTLY to registers (no LDS hop), x
// prefetched one step ahead, x-projection MFMAs overlap the barrier wait.

#define NB 256
#define NH 512
#define NI 128
#define NC 1000
#define NS 512

typedef __attribute__((ext_vector_type(8))) short bf16x8;
typedef __attribute__((ext_vector_type(4))) float f32x4;

__device__ __forceinline__ unsigned short f2bf(float f) {
    unsigned u = __builtin_bit_cast(unsigned, f);
    return (unsigned short)((u + 0x7FFFu + ((u >> 16) & 1u)) >> 16);  // RNE
}

__device__ __forceinline__ unsigned long long ld_agent_u64(const unsigned long long* p) {
    return __hip_atomic_load(p, __ATOMIC_RELAXED, __HIP_MEMORY_SCOPE_AGENT);
}
__device__ __forceinline__ unsigned int ld_agent_u32(const unsigned int* p) {
    return __hip_atomic_load(p, __ATOMIC_RELAXED, __HIP_MEMORY_SCOPE_AGENT);
}
__device__ __forceinline__ void st_agent_u16(unsigned short* p, unsigned short v) {
    __hip_atomic_store(p, v, __ATOMIC_RELAXED, __HIP_MEMORY_SCOPE_AGENT);
}
__device__ __forceinline__ void st_agent_u32(unsigned int* p, unsigned int v) {
    __hip_atomic_store(p, v, __ATOMIC_RELAXED, __HIP_MEMORY_SCOPE_AGENT);
}

__global__ void gru_init_ws(unsigned int* __restrict__ fl) {
    const int i = blockIdx.x * 256 + threadIdx.x;
    if (i < 512) fl[i] = 0u;
}

// 128 blocks x 256 threads. g=bid&15 (rows 16g..16g+16; all 8 blocks of a
// group land on one XCD under bid%8 round-robin -- perf heuristic only),
// jb=bid>>4 (cols 64jb..64jb+64). Wave w owns 16 cols, full K=512.
// hbuf: [2][16 g][16 frag][512] bf16; frag f holds A-fragment of 16 rows x
// 32 k: elem(lane l, e) = h[row=l&15][k=f*32+(l>>4)*8+e].
__global__ void __launch_bounds__(256, 1) gru_scan(
    const float* __restrict__ x,
    const float* __restrict__ Wih,
    const float* __restrict__ Whh,
    const float* __restrict__ bih,
    const float* __restrict__ bhh,
    unsigned short* __restrict__ hbuf,
    float* __restrict__ hT,
    unsigned int* __restrict__ flags)    // [16 groups][32] u32 (128B stride)
{
    const int tid = threadIdx.x;
    const int l   = tid & 63;
    const int w   = tid >> 6;
    const int l15 = l & 15;
    const int lq  = l >> 4;
    const int bid = blockIdx.x;
    const int g   = bid & 15;
    const int jb  = bid >> 4;
    const int c   = jb * 64 + w * 16 + l15;   // this lane's output col

    // ---- weights -> bf16 fragments in VGPRs ----
    // B-frag (16x16x32): lane holds W[col=l&15 of wave tile][k=(l>>4)*8+0..7]
    bf16x8 whh[3][16];
#pragma unroll
    for (int gt = 0; gt < 3; ++gt) {
        const float* wr = Whh + (size_t)(gt * NH + c) * NH;
#pragma unroll
        for (int ks = 0; ks < 16; ++ks) {
            float tmp[8];
            *(f32x4*)(tmp)     = *(const f32x4*)(wr + ks * 32 + lq * 8);
            *(f32x4*)(tmp + 4) = *(const f32x4*)(wr + ks * 32 + lq * 8 + 4);
            bf16x8 r;
#pragma unroll
            for (int i = 0; i < 8; ++i) r[i] = (short)f2bf(tmp[i]);
            whh[gt][ks] = r;
        }
    }
    bf16x8 wih[3][4];
#pragma unroll
    for (int gt = 0; gt < 3; ++gt) {
        const float* wr = Wih + (size_t)(gt * NH + c) * NI;
#pragma unroll
        for (int ks = 0; ks < 4; ++ks) {
            float tmp[8];
            *(f32x4*)(tmp)     = *(const f32x4*)(wr + ks * 32 + lq * 8);
            *(f32x4*)(tmp + 4) = *(const f32x4*)(wr + ks * 32 + lq * 8 + 4);
            bf16x8 r;
#pragma unroll
            for (int i = 0; i < 8; ++i) r[i] = (short)f2bf(tmp[i]);
            wih[gt][ks] = r;
        }
    }

    const float bR  = bih[c] + bhh[c];
    const float bZ  = bih[NH + c] + bhh[NH + c];
    const float bNx = bih[2 * NH + c];
    const float bNh = bhh[2 * NH + c];

    float hprev[4] = {0.f, 0.f, 0.f, 0.f};  // rows lq*4+0..3, col c

    const float* xrow = x + (size_t)(g * 16 + l15) * (NS * NI) + lq * 8;
    unsigned int* fl = flags + g * 32;

    // producer-side store mapping (into fragment layout)
    const int Fst   = jb * 2 + (w >> 1);                       // frag index
    const int lanep = ((w & 1) * 2 + (l15 >> 3)) * 16;         // lane' base
    const int est   = l15 & 7;                                 // elem

    // prefetch x for t=0 (raw f32)
    f32x4 xn[8];
#pragma unroll
    for (int ks = 0; ks < 4; ++ks) {
        xn[2 * ks]     = *(const f32x4*)(xrow + ks * 32);
        xn[2 * ks + 1] = *(const f32x4*)(xrow + ks * 32 + 4);
    }

    for (int t = 0; t < NS; ++t) {
        const int rb = t & 1, wb = rb ^ 1;

        // ---- pack prefetched x -> bf16 fragments ----
        bf16x8 xf[4];
#pragma unroll
        for (int ks = 0; ks < 4; ++ks) {
            float tmp[8];
            *(f32x4*)(tmp)     = xn[2 * ks];
            *(f32x4*)(tmp + 4) = xn[2 * ks + 1];
            bf16x8 r;
#pragma unroll
            for (int i = 0; i < 8; ++i) r[i] = (short)f2bf(tmp[i]);
            xf[ks] = r;
        }

        // ---- x-projection MFMAs BEFORE the poll (independent of h) ----
        f32x4 aR  = {bR, bR, bR, bR};
        f32x4 aZ  = {bZ, bZ, bZ, bZ};
        f32x4 aNx = {bNx, bNx, bNx, bNx};
        f32x4 aNh = {bNh, bNh, bNh, bNh};
#pragma unroll
        for (int ks = 0; ks < 4; ++ks) {
            aR  = __builtin_amdgcn_mfma_f32_16x16x32_bf16(xf[ks], wih[0][ks], aR, 0, 0, 0);
            aZ  = __builtin_amdgcn_mfma_f32_16x16x32_bf16(xf[ks], wih[1][ks], aZ, 0, 0, 0);
            aNx = __builtin_amdgcn_mfma_f32_16x16x32_bf16(xf[ks], wih[2][ks], aNx, 0, 0, 0);
        }

        // ---- issue x prefetch for t+1 (overlaps wait + h phase) ----
        if (t + 1 < NS) {
            const float* xt = xrow + (size_t)(t + 1) * NI;
#pragma unroll
            for (int ks = 0; ks < 4; ++ks) {
                xn[2 * ks]     = *(const f32x4*)(xt + ks * 32);
                xn[2 * ks + 1] = *(const f32x4*)(xt + ks * 32 + 4);
            }
        }

        if (t > 0) {
            // ---- group barrier: poll 8 per-block flags (lane-parallel) ----
            unsigned int myf;
            do { myf = ld_agent_u32(fl + (l & 7)); }
            while (!__all((int)(myf >= (unsigned)t)));
            __builtin_amdgcn_sched_barrier(0);
            asm volatile("" ::: "memory");

            // ---- h A-frags: IC -> registers directly (no LDS hop) ----
            const unsigned long long* hq =
                (const unsigned long long*)(hbuf + ((size_t)rb * 16 + g) * (16 * 512));
            bf16x8 afr[16];
#pragma unroll
            for (int f = 0; f < 16; ++f) {
                union { unsigned long long q[2]; bf16x8 v; } u;
                u.q[0] = ld_agent_u64(hq + f * 128 + (l << 1));
                u.q[1] = ld_agent_u64(hq + f * 128 + (l << 1) + 1);
                afr[f] = u.v;
            }
            // ---- hidden-projection MFMAs (48, full K=512) ----
#pragma unroll
            for (int ks = 0; ks < 16; ++ks) {
                aR  = __builtin_amdgcn_mfma_f32_16x16x32_bf16(afr[ks], whh[0][ks], aR, 0, 0, 0);
                aZ  = __builtin_amdgcn_mfma_f32_16x16x32_bf16(afr[ks], whh[1][ks], aZ, 0, 0, 0);
                aNh = __builtin_amdgcn_mfma_f32_16x16x32_bf16(afr[ks], whh[2][ks], aNh, 0, 0, 0);
            }
        }

        // ---- gates (fp32, in-lane) ----
        float hnew[4];
#pragma unroll
        for (int i = 0; i < 4; ++i) {
            const float rr = __builtin_amdgcn_rcpf(1.f + __expf(-aR[i]));
            const float zz = __builtin_amdgcn_rcpf(1.f + __expf(-aZ[i]));
            const float a  = aNx[i] + rr * aNh[i];
            const float e2 = __expf(2.f * a);
            const float nn = (e2 - 1.f) * __builtin_amdgcn_rcpf(e2 + 1.f);
            hnew[i] = (1.f - zz) * nn + zz * hprev[i];
            hprev[i] = hnew[i];
        }

        if (t < NS - 1) {
            // ---- publish h(t+1) in fragment layout (sc1 -> IC) ----
            unsigned short* dst = hbuf + (((size_t)wb * 16 + g) * 16 + Fst) * 512;
#pragma unroll
            for (int i = 0; i < 4; ++i) {
                const int rl = lq * 4 + i;
                st_agent_u16(dst + (lanep + rl) * 8 + est, f2bf(hnew[i]));
            }
            asm volatile("s_waitcnt vmcnt(0)" ::: "memory");  // h stores ack'd at IC
            __syncthreads();                                  // all 4 waves drained
            if (tid == 0) st_agent_u32(&fl[jb], (unsigned)(t + 1));
        } else {
            // final state -> hT (fp32, plain stores; flushed at kernel end)
#pragma unroll
            for (int i = 0; i < 4; ++i)
                hT[(size_t)(g * 16 + lq * 4 + i) * NH + c] = hnew[i];
        }
    }
}

// out[256,1000] = hT[256,512] @ W_head^T + b_head, pure fp32.
__global__ void __launch_bounds__(256, 1) gru_head(
    const float* __restrict__ hT,
    const float* __restrict__ Wh,
    const float* __restrict__ bh,
    float* __restrict__ out)
{
    __shared__ float hs[16 * 512];
    const int tid = threadIdx.x;
    const int rg  = blockIdx.x;
    const int cgp = blockIdx.y;
    const float* src = hT + rg * (16 * 512);
#pragma unroll
    for (int i = 0; i < 32; ++i) hs[tid + 256 * i] = src[tid + 256 * i];
    __syncthreads();
    const int col = (cgp << 6) + (tid & 63);
    const int rb  = (tid >> 6) << 2;
    if (col < NC) {
        const float* wr = Wh + col * NH;
        float a0 = 0.f, a1 = 0.f, a2 = 0.f, a3 = 0.f;
        for (int k = 0; k < NH; k += 4) {
            const f32x4 wv = *(const f32x4*)(wr + k);
            const f32x4 h0 = *(const f32x4*)&hs[(rb + 0) * NH + k];
            const f32x4 h1 = *(const f32x4*)&hs[(rb + 1) * NH + k];
            const f32x4 h2 = *(const f32x4*)&hs[(rb + 2) * NH + k];
            const f32x4 h3 = *(const f32x4*)&hs[(rb + 3) * NH + k];
#pragma unroll
            for (int j = 0; j < 4; ++j) {
                a0 = fmaf(wv[j], h0[j], a0);
                a1 = fmaf(wv[j], h1[j], a1);
                a2 = fmaf(wv[j], h2[j], a2);
                a3 = fmaf(wv[j], h3[j], a3);
            }
        }
        const float bb = bh[col];
        const int orow = (rg << 4) + rb;
        out[(orow + 0) * NC + col] = a0 + bb;
        out[(orow + 1) * NC + col] = a1 + bb;
        out[(orow + 2) * NC + col] = a2 + bb;
        out[(orow + 3) * NC + col] = a3 + bb;
    }
}

extern "C" void kernel_launch(void* const* d_in, const int* in_sizes, int n_in,
                              void* d_out, int out_size, void* d_ws, size_t ws_size,
                              hipStream_t stream)
{
    (void)in_sizes; (void)n_in; (void)out_size; (void)ws_size;
    const float* x     = (const float*)d_in[0];
    const float* Wih   = (const float*)d_in[1];
    const float* Whh   = (const float*)d_in[2];
    const float* bih   = (const float*)d_in[3];
    const float* bhh   = (const float*)d_in[4];
    const float* Whead = (const float*)d_in[5];
    const float* bhead = (const float*)d_in[6];
    float* out = (float*)d_out;

    char* ws = (char*)d_ws;
    unsigned short* hbuf  = (unsigned short*)ws;                  // 2*16*16*512*2B = 512KB
    unsigned int*   flags = (unsigned int*)(ws + 512 * 1024);     // 512 u32 = 2KB
    float*          hT    = (float*)(ws + 512 * 1024 + 2048);     // 512KB

    gru_init_ws<<<2, 256, 0, stream>>>(flags);
    gru_scan<<<128, 256, 0, stream>>>(x, Wih, Whh, bih, bhh, hbuf, hT, flags);
    gru_head<<<dim3(16, 16), 256, 0, stream>>>(hT, Whead, bhead, out);
}

// Round 9
// 1938.176 us; speedup vs baseline: 1.3785x; 1.3785x over previous
//
#include <hip/hip_runtime.h>

// GRU classifier: x[256,512,128] -> GRU(H=512) -> head -> out[256,1000]
// R6 = R3 resource profile (256 blocks, 32 cols/block, 2-way K-split, ~152
// VGPR, no spill) + flag-store barrier (no RMW), fragment-layout h exchange
// (coalesced IC->reg), x-proj MFMAs before the poll, 4-vector LDS reduce.

#define NB 256
#define NH 512
#define NI 128
#define NC 1000
#define NS 512

typedef __attribute__((ext_vector_type(8))) short bf16x8;
typedef __attribute__((ext_vector_type(4))) float f32x4;

__device__ __forceinline__ unsigned short f2bf(float f) {
    unsigned u = __builtin_bit_cast(unsigned, f);
    return (unsigned short)((u + 0x7FFFu + ((u >> 16) & 1u)) >> 16);  // RNE
}

__device__ __forceinline__ bf16x8 pack8(const float* v) {
    bf16x8 r;
#pragma unroll
    for (int i = 0; i < 8; ++i) r[i] = (short)f2bf(v[i]);
    return r;
}

__device__ __forceinline__ unsigned long long ld_agent_u64(const unsigned long long* p) {
    return __hip_atomic_load(p, __ATOMIC_RELAXED, __HIP_MEMORY_SCOPE_AGENT);
}
__device__ __forceinline__ unsigned int ld_agent_u32(const unsigned int* p) {
    return __hip_atomic_load(p, __ATOMIC_RELAXED, __HIP_MEMORY_SCOPE_AGENT);
}
__device__ __forceinline__ void st_agent_u16(unsigned short* p, unsigned short v) {
    __hip_atomic_store(p, v, __ATOMIC_RELAXED, __HIP_MEMORY_SCOPE_AGENT);
}
__device__ __forceinline__ void st_agent_u32(unsigned int* p, unsigned int v) {
    __hip_atomic_store(p, v, __ATOMIC_RELAXED, __HIP_MEMORY_SCOPE_AGENT);
}

__global__ void gru_init_ws(unsigned int* __restrict__ fl) {
    const int i = blockIdx.x * 256 + threadIdx.x;
    if (i < 512) fl[i] = 0u;
}

// 256 blocks x 256 threads. g=bid&15 (rows 16g..16g+16), jb=bid>>4 (0..15,
// cols 32jb..32jb+32). Waves: ch=w&1 (16-col half), kh=w>>1 (K-half of 256).
// hbuf: [2][16 g][16 frag][512] bf16. Frag f = A-fragment of h rows 16g..+16,
// k=32f..32f+32: elem(lane',e) = h[row=lane'&15][k=f*32+(lane'>>4)*8+e].
// Block jb's 32 cols == frag jb exactly.
__global__ void __launch_bounds__(256, 1) gru_scan(
    const float* __restrict__ x,
    const float* __restrict__ Wih,
    const float* __restrict__ Whh,
    const float* __restrict__ bih,
    const float* __restrict__ bhh,
    unsigned short* __restrict__ hbuf,
    float* __restrict__ hT,
    unsigned int* __restrict__ flags)    // [16 groups][32] u32 (128B stride)
{
    const int tid = threadIdx.x;
    const int l   = tid & 63;
    const int w   = tid >> 6;
    const int ch  = w & 1;
    const int kh  = w >> 1;
    const int bid = blockIdx.x;
    const int g   = bid & 15;
    const int jb  = bid >> 4;
    const int r0  = g << 4;
    const int cw0 = (jb << 5) + (ch << 4);
    const int l15 = l & 15;
    const int lq  = l >> 4;
    const int c_col = cw0 + l15;

    __shared__ float part[4][4][64][4];  // 16KB: cross-wave K-half reduce

    // ---- weights -> bf16 fragments in VGPRs (K-half per wave) ----
    bf16x8 whh[3][8];
#pragma unroll
    for (int gt = 0; gt < 3; ++gt) {
        const float* wr = Whh + (size_t)(gt * NH + c_col) * NH;
#pragma unroll
        for (int ks = 0; ks < 8; ++ks) {
            const int k0 = kh * 256 + ks * 32 + lq * 8;
            float tmp[8];
            *(f32x4*)(tmp)     = *(const f32x4*)(wr + k0);
            *(f32x4*)(tmp + 4) = *(const f32x4*)(wr + k0 + 4);
            whh[gt][ks] = pack8(tmp);
        }
    }
    bf16x8 wih[3][2];
#pragma unroll
    for (int gt = 0; gt < 3; ++gt) {
        const float* wr = Wih + (size_t)(gt * NH + c_col) * NI;
#pragma unroll
        for (int ks = 0; ks < 2; ++ks) {
            const int k0 = kh * 64 + ks * 32 + lq * 8;
            float tmp[8];
            *(f32x4*)(tmp)     = *(const f32x4*)(wr + k0);
            *(f32x4*)(tmp + 4) = *(const f32x4*)(wr + k0 + 4);
            wih[gt][ks] = pack8(tmp);
        }
    }

    float bR = bih[c_col] + bhh[c_col];
    float bZ = bih[NH + c_col] + bhh[NH + c_col];
    float bNx = bih[2 * NH + c_col];
    float bNh = bhh[2 * NH + c_col];
    if (kh != 0) { bR = bZ = bNx = bNh = 0.f; }  // bias counted once per col

    float hold0 = 0.f, hold1 = 0.f;  // rows lq*4+kh*2+{0,1}, col c_col

    const float* xptr0 = x + (size_t)(r0 + l15) * (NS * NI) + kh * 64 + lq * 8;
    unsigned int* fl = flags + g * 32;

    // producer store mapping into frag jb: lane' = (ch*2+(l15>>3))*16 + row'
    const int lanep8 = ((ch * 2 + (l15 >> 3)) * 16 + lq * 4 + kh * 2) * 8;
    const int est    = l15 & 7;

    // x prefetch for t=0
    f32x4 xp0 = *(const f32x4*)(xptr0 + 0);
    f32x4 xp1 = *(const f32x4*)(xptr0 + 4);
    f32x4 xp2 = *(const f32x4*)(xptr0 + 32);
    f32x4 xp3 = *(const f32x4*)(xptr0 + 36);

    for (int t = 0; t < NS; ++t) {
        const int rb = t & 1, wb = rb ^ 1;

        // ---- pack prefetched x, x-projection MFMAs (independent of h) ----
        f32x4 aR = {bR, bR, bR, bR}, aZ = {bZ, bZ, bZ, bZ};
        f32x4 aNx = {bNx, bNx, bNx, bNx}, aNh = {bNh, bNh, bNh, bNh};
        {
            float xt[16];
            *(f32x4*)(xt)      = xp0; *(f32x4*)(xt + 4)  = xp1;
            *(f32x4*)(xt + 8)  = xp2; *(f32x4*)(xt + 12) = xp3;
            bf16x8 xf0 = pack8(xt), xf1 = pack8(xt + 8);
            aR  = __builtin_amdgcn_mfma_f32_16x16x32_bf16(xf0, wih[0][0], aR, 0, 0, 0);
            aZ  = __builtin_amdgcn_mfma_f32_16x16x32_bf16(xf0, wih[1][0], aZ, 0, 0, 0);
            aNx = __builtin_amdgcn_mfma_f32_16x16x32_bf16(xf0, wih[2][0], aNx, 0, 0, 0);
            aR  = __builtin_amdgcn_mfma_f32_16x16x32_bf16(xf1, wih[0][1], aR, 0, 0, 0);
            aZ  = __builtin_amdgcn_mfma_f32_16x16x32_bf16(xf1, wih[1][1], aZ, 0, 0, 0);
            aNx = __builtin_amdgcn_mfma_f32_16x16x32_bf16(xf1, wih[2][1], aNx, 0, 0, 0);
        }

        if (t > 0) {
            // ---- group barrier: poll 16 per-block flags (lane-parallel) ----
            unsigned int myf;
            do { myf = ld_agent_u32(fl + (l & 15)); }
            while (!__all((int)(myf >= (unsigned)t)));
            __builtin_amdgcn_sched_barrier(0);
            asm volatile("" ::: "memory");

            // ---- h A-frags: coalesced IC -> registers (K-half: 8 frags) ----
            const unsigned long long* hq =
                (const unsigned long long*)(hbuf + (((size_t)rb * 16 + g) * 16 + kh * 8) * 512);
            bf16x8 afr[8];
#pragma unroll
            for (int f = 0; f < 8; ++f) {
                union { unsigned long long q[2]; bf16x8 v; } u;
                u.q[0] = ld_agent_u64(hq + f * 128 + (l << 1));
                u.q[1] = ld_agent_u64(hq + f * 128 + (l << 1) + 1);
                afr[f] = u.v;
            }

            // x prefetch t+1 (overlaps h-load/MFMA latency)
            if (t + 1 < NS) {
                const float* xp = xptr0 + (size_t)(t + 1) * NI;
                xp0 = *(const f32x4*)(xp + 0);
                xp1 = *(const f32x4*)(xp + 4);
                xp2 = *(const f32x4*)(xp + 32);
                xp3 = *(const f32x4*)(xp + 36);
            }

            // ---- hidden-projection MFMAs (24, K-half) ----
#pragma unroll
            for (int ks = 0; ks < 8; ++ks) {
                aR  = __builtin_amdgcn_mfma_f32_16x16x32_bf16(afr[ks], whh[0][ks], aR, 0, 0, 0);
                aZ  = __builtin_amdgcn_mfma_f32_16x16x32_bf16(afr[ks], whh[1][ks], aZ, 0, 0, 0);
                aNh = __builtin_amdgcn_mfma_f32_16x16x32_bf16(afr[ks], whh[2][ks], aNh, 0, 0, 0);
            }
        } else {
            // t=0: x prefetch for t=1
            const float* xp = xptr0 + NI;
            xp0 = *(const f32x4*)(xp + 0);
            xp1 = *(const f32x4*)(xp + 4);
            xp2 = *(const f32x4*)(xp + 32);
            xp3 = *(const f32x4*)(xp + 36);
        }

        // ---- cross-wave K-half reduction via LDS (4 vectors) ----
        *(f32x4*)&part[w][0][l][0] = aR;
        *(f32x4*)&part[w][1][l][0] = aZ;
        *(f32x4*)&part[w][2][l][0] = aNx;
        *(f32x4*)&part[w][3][l][0] = aNh;
        __syncthreads();
        const int pw = w ^ 2;  // partner: same ch, other kh
        const f32x4 pR  = *(const f32x4*)&part[pw][0][l][0];
        const f32x4 pZ  = *(const f32x4*)&part[pw][1][l][0];
        const f32x4 pXn = *(const f32x4*)&part[pw][2][l][0];
        const f32x4 pHn = *(const f32x4*)&part[pw][3][l][0];

        // wave kh keeps accumulator elems {kh*2, kh*2+1} (rows lq*4+kh*2+q)
        const int i0 = kh * 2;
        float vR[2], vZ[2], vXn[2], vHn[2];
#pragma unroll
        for (int q = 0; q < 2; ++q) {
            vR[q]  = aR[i0 + q]  + pR[i0 + q];
            vZ[q]  = aZ[i0 + q]  + pZ[i0 + q];
            vXn[q] = aNx[i0 + q] + pXn[i0 + q];
            vHn[q] = aNh[i0 + q] + pHn[i0 + q];
        }

        // ---- gates + state update (fp32 carry) ----
        unsigned short* dst = hbuf + (((size_t)wb * 16 + g) * 16 + jb) * 512;
#pragma unroll
        for (int q = 0; q < 2; ++q) {
            const float rr = __builtin_amdgcn_rcpf(1.f + __expf(-vR[q]));
            const float zz = __builtin_amdgcn_rcpf(1.f + __expf(-vZ[q]));
            const float a  = vXn[q] + rr * vHn[q];
            const float e2 = __expf(2.f * a);
            const float nn = (e2 - 1.f) * __builtin_amdgcn_rcpf(e2 + 1.f);
            const float hp = q ? hold1 : hold0;
            const float hnew = (1.f - zz) * nn + zz * hp;
            if (q) hold1 = hnew; else hold0 = hnew;
            if (t < NS - 1) {
                st_agent_u16(dst + lanep8 + q * 8 + est, f2bf(hnew));
            } else {
                hT[(size_t)(r0 + lq * 4 + kh * 2 + q) * NH + c_col] = hnew;
            }
        }

        if (t < NS - 1) {
            asm volatile("s_waitcnt vmcnt(0)" ::: "memory");  // h stores ack'd at IC
            __syncthreads();                                  // all 4 waves drained
            if (tid == 0) st_agent_u32(&fl[jb], (unsigned)(t + 1));
        }
    }
}

// out[256,1000] = hT[256,512] @ W_head^T + b_head, pure fp32.
__global__ void __launch_bounds__(256, 1) gru_head(
    const float* __restrict__ hT,
    const float* __restrict__ Wh,
    const float* __restrict__ bh,
    float* __restrict__ out)
{
    __shared__ float hs[16 * 512];
    const int tid = threadIdx.x;
    const int rg  = blockIdx.x;
    const int cgp = blockIdx.y;
    const float* src = hT + rg * (16 * 512);
#pragma unroll
    for (int i = 0; i < 32; ++i) hs[tid + 256 * i] = src[tid + 256 * i];
    __syncthreads();
    const int col = (cgp << 6) + (tid & 63);
    const int rb  = (tid >> 6) << 2;
    if (col < NC) {
        const float* wr = Wh + col * NH;
        float a0 = 0.f, a1 = 0.f, a2 = 0.f, a3 = 0.f;
        for (int k = 0; k < NH; k += 4) {
            const f32x4 wv = *(const f32x4*)(wr + k);
            const f32x4 h0 = *(const f32x4*)&hs[(rb + 0) * NH + k];
            const f32x4 h1 = *(const f32x4*)&hs[(rb + 1) * NH + k];
            const f32x4 h2 = *(const f32x4*)&hs[(rb + 2) * NH + k];
            const f32x4 h3 = *(const f32x4*)&hs[(rb + 3) * NH + k];
#pragma unroll
            for (int j = 0; j < 4; ++j) {
                a0 = fmaf(wv[j], h0[j], a0);
                a1 = fmaf(wv[j], h1[j], a1);
                a2 = fmaf(wv[j], h2[j], a2);
                a3 = fmaf(wv[j], h3[j], a3);
            }
        }
        const float bb = bh[col];
        const int orow = (rg << 4) + rb;
        out[(orow + 0) * NC + col] = a0 + bb;
        out[(orow + 1) * NC + col] = a1 + bb;
        out[(orow + 2) * NC + col] = a2 + bb;
        out[(orow + 3) * NC + col] = a3 + bb;
    }
}

extern "C" void kernel_launch(void* const* d_in, const int* in_sizes, int n_in,
                              void* d_out, int out_size, void* d_ws, size_t ws_size,
                              hipStream_t stream)
{
    (void)in_sizes; (void)n_in; (void)out_size; (void)ws_size;
    const float* x     = (const float*)d_in[0];
    const float* Wih   = (const float*)d_in[1];
    const float* Whh   = (const float*)d_in[2];
    const float* bih   = (const float*)d_in[3];
    const float* bhh   = (const float*)d_in[4];
    const float* Whead = (const float*)d_in[5];
    const float* bhead = (const float*)d_in[6];
    float* out = (float*)d_out;

    char* ws = (char*)d_ws;
    unsigned short* hbuf  = (unsigned short*)ws;                  // 2*16*16*512*2B = 512KB
    unsigned int*   flags = (unsigned int*)(ws + 512 * 1024);     // 512 u32 = 2KB
    float*          hT    = (float*)(ws + 512 * 1024 + 2048);     // 512KB

    gru_init_ws<<<2, 256, 0, stream>>>(flags);
    gru_scan<<<256, 256, 0, stream>>>(x, Wih, Whh, bih, bhh, hbuf, hT, flags);
    gru_head<<<dim3(16, 16), 256, 0, stream>>>(hT, Whead, bhead, out);
}

// Round 10
// 1699.677 us; speedup vs baseline: 1.5720x; 1.1403x over previous
//
#include <hip/hip_runtime.h>

// GRU classifier: x[256,512,128] -> GRU(H=512) -> head -> out[256,1000]
// R7 = R6 skeleton with IC-transaction fixes: swapped MFMA operands so each
// lane owns 4 consecutive h-cols of one batch row -> ONE u64 sc1 store/lane;
// wave0-only poll with s_sleep backoff + syncthreads release; x-proj shadows
// the store drain; x prefetch issued after the flag.

#define NB 256
#define NH 512
#define NI 128
#define NC 1000
#define NS 512

typedef __attribute__((ext_vector_type(8))) short bf16x8;
typedef __attribute__((ext_vector_type(4))) float f32x4;

__device__ __forceinline__ unsigned short f2bf(float f) {
    unsigned u = __builtin_bit_cast(unsigned, f);
    return (unsigned short)((u + 0x7FFFu + ((u >> 16) & 1u)) >> 16);  // RNE
}

__device__ __forceinline__ bf16x8 pack8(const float* v) {
    bf16x8 r;
#pragma unroll
    for (int i = 0; i < 8; ++i) r[i] = (short)f2bf(v[i]);
    return r;
}

__device__ __forceinline__ unsigned long long ld_agent_u64(const unsigned long long* p) {
    return __hip_atomic_load(p, __ATOMIC_RELAXED, __HIP_MEMORY_SCOPE_AGENT);
}
__device__ __forceinline__ unsigned int ld_agent_u32(const unsigned int* p) {
    return __hip_atomic_load(p, __ATOMIC_RELAXED, __HIP_MEMORY_SCOPE_AGENT);
}
__device__ __forceinline__ void st_agent_u64(unsigned long long* p, unsigned long long v) {
    __hip_atomic_store(p, v, __ATOMIC_RELAXED, __HIP_MEMORY_SCOPE_AGENT);
}
__device__ __forceinline__ void st_agent_u32(unsigned int* p, unsigned int v) {
    __hip_atomic_store(p, v, __ATOMIC_RELAXED, __HIP_MEMORY_SCOPE_AGENT);
}

__global__ void gru_init_ws(unsigned int* __restrict__ fl) {
    const int i = blockIdx.x * 256 + threadIdx.x;
    if (i < 512) fl[i] = 0u;
}

// 256 blocks x 256 threads. g=bid&15 (rows 16g..16g+16), jb=bid>>4 (0..15,
// cols 32jb..32jb+32 == frag jb). Waves: ch=w&1 (16-col half), kh=w>>1 (K-half).
// hbuf: [2][16 g][16 frag][512] bf16. Frag f: elem(lane',e) =
//   h[row = lane'&15][k = f*32 + (lane'>>4)*8 + e].
// MFMA operands SWAPPED (A=W, B=h/x): D[row=gate-col][col=batch], so lane
// holds batch=l&15, gate-cols cw0+lq*4+{0..3} -> contiguous u64 h publish.
__global__ void __launch_bounds__(256, 1) gru_scan(
    const float* __restrict__ x,
    const float* __restrict__ Wih,
    const float* __restrict__ Whh,
    const float* __restrict__ bih,
    const float* __restrict__ bhh,
    unsigned short* __restrict__ hbuf,
    float* __restrict__ hT,
    unsigned int* __restrict__ flags)    // [16 groups][32] u32 (128B stride)
{
    const int tid = threadIdx.x;
    const int l   = tid & 63;
    const int w   = tid >> 6;
    const int ch  = w & 1;
    const int kh  = w >> 1;
    const int bid = blockIdx.x;
    const int g   = bid & 15;
    const int jb  = bid >> 4;
    const int r0  = g << 4;
    const int cw0 = (jb << 5) + (ch << 4);
    const int l15 = l & 15;
    const int lq  = l >> 4;
    const int c_col = cw0 + l15;

    __shared__ float part[4][4][64][4];  // 16KB cross-wave K-half reduce

    // ---- weights -> bf16 fragments in VGPRs (K-half per wave) ----
    // frag: lane holds W[idx = l&15][k = (l>>4)*8 + e]  (dual A/B layout)
    bf16x8 whh[3][8];
#pragma unroll
    for (int gt = 0; gt < 3; ++gt) {
        const float* wr = Whh + (size_t)(gt * NH + c_col) * NH;
#pragma unroll
        for (int ks = 0; ks < 8; ++ks) {
            const int k0 = kh * 256 + ks * 32 + lq * 8;
            float tmp[8];
            *(f32x4*)(tmp)     = *(const f32x4*)(wr + k0);
            *(f32x4*)(tmp + 4) = *(const f32x4*)(wr + k0 + 4);
            whh[gt][ks] = pack8(tmp);
        }
    }
    bf16x8 wih[3][2];
#pragma unroll
    for (int gt = 0; gt < 3; ++gt) {
        const float* wr = Wih + (size_t)(gt * NH + c_col) * NI;
#pragma unroll
        for (int ks = 0; ks < 2; ++ks) {
            const int k0 = kh * 64 + ks * 32 + lq * 8;
            float tmp[8];
            *(f32x4*)(tmp)     = *(const f32x4*)(wr + k0);
            *(f32x4*)(tmp + 4) = *(const f32x4*)(wr + k0 + 4);
            wih[gt][ks] = pack8(tmp);
        }
    }

    // per-lane VECTOR biases (cols cw0+lq*4+i); kh1 waves carry zero
    f32x4 bRv = {0.f,0.f,0.f,0.f}, bZv = bRv, bNxv = bRv, bNhv = bRv;
    if (kh == 0) {
#pragma unroll
        for (int i = 0; i < 4; ++i) {
            const int col = cw0 + lq * 4 + i;
            bRv[i]  = bih[col] + bhh[col];
            bZv[i]  = bih[NH + col] + bhh[NH + col];
            bNxv[i] = bih[2 * NH + col];
            bNhv[i] = bhh[2 * NH + col];
        }
    }

    float hold[4] = {0.f, 0.f, 0.f, 0.f};  // batch l15, cols cw0+lq*4+i (kh0)

    const float* xptr0 = x + (size_t)(r0 + l15) * (NS * NI) + kh * 64 + lq * 8;
    unsigned int* fl = flags + g * 32;

    // h publish mapping: frag jb, lane' = (2ch + (lq>>1))*16 + l15
    const int u64idx = ((2 * ch + (lq >> 1)) * 16 + l15) * 2 + (lq & 1);

    // ---- prologue: x(0) -> acc, prefetch x(1) ----
    f32x4 xp0 = *(const f32x4*)(xptr0 + 0);
    f32x4 xp1 = *(const f32x4*)(xptr0 + 4);
    f32x4 xp2 = *(const f32x4*)(xptr0 + 32);
    f32x4 xp3 = *(const f32x4*)(xptr0 + 36);

    f32x4 aR, aZ, aNx, aNh;
    {
        float xt[16];
        *(f32x4*)(xt)      = xp0; *(f32x4*)(xt + 4)  = xp1;
        *(f32x4*)(xt + 8)  = xp2; *(f32x4*)(xt + 12) = xp3;
        bf16x8 xf0 = pack8(xt), xf1 = pack8(xt + 8);
        aR = bRv; aZ = bZv; aNx = bNxv; aNh = bNhv;
        aR  = __builtin_amdgcn_mfma_f32_16x16x32_bf16(wih[0][0], xf0, aR, 0, 0, 0);
        aZ  = __builtin_amdgcn_mfma_f32_16x16x32_bf16(wih[1][0], xf0, aZ, 0, 0, 0);
        aNx = __builtin_amdgcn_mfma_f32_16x16x32_bf16(wih[2][0], xf0, aNx, 0, 0, 0);
        aR  = __builtin_amdgcn_mfma_f32_16x16x32_bf16(wih[0][1], xf1, aR, 0, 0, 0);
        aZ  = __builtin_amdgcn_mfma_f32_16x16x32_bf16(wih[1][1], xf1, aZ, 0, 0, 0);
        aNx = __builtin_amdgcn_mfma_f32_16x16x32_bf16(wih[2][1], xf1, aNx, 0, 0, 0);
    }
    {   // prefetch x(1)
        const float* xp = xptr0 + NI;
        xp0 = *(const f32x4*)(xp + 0);
        xp1 = *(const f32x4*)(xp + 4);
        xp2 = *(const f32x4*)(xp + 32);
        xp3 = *(const f32x4*)(xp + 36);
    }

    for (int t = 0; t < NS; ++t) {
        const int rb = t & 1, wb = rb ^ 1;

        if (t > 0) {
            // ---- wave0-only poll with backoff, then barrier release ----
            if (w == 0) {
                unsigned int myf = ld_agent_u32(fl + l15);
                while (!__all((int)(myf >= (unsigned)t))) {
                    __builtin_amdgcn_s_sleep(1);
                    myf = ld_agent_u32(fl + (l & 15));
                }
            }
            __syncthreads();

            // ---- h frags: coalesced IC -> registers (K-half: 8 frags) ----
            const unsigned long long* hq =
                (const unsigned long long*)(hbuf + (((size_t)rb * 16 + g) * 16 + kh * 8) * 512);
            bf16x8 afr[8];
#pragma unroll
            for (int f = 0; f < 8; ++f) {
                union { unsigned long long q[2]; bf16x8 v; } u;
                u.q[0] = ld_agent_u64(hq + f * 128 + (l << 1));
                u.q[1] = ld_agent_u64(hq + f * 128 + (l << 1) + 1);
                afr[f] = u.v;
            }
            // ---- hidden-projection MFMAs (24, K-half, swapped operands) ----
#pragma unroll
            for (int ks = 0; ks < 8; ++ks) {
                aR  = __builtin_amdgcn_mfma_f32_16x16x32_bf16(whh[0][ks], afr[ks], aR, 0, 0, 0);
                aZ  = __builtin_amdgcn_mfma_f32_16x16x32_bf16(whh[1][ks], afr[ks], aZ, 0, 0, 0);
                aNh = __builtin_amdgcn_mfma_f32_16x16x32_bf16(whh[2][ks], afr[ks], aNh, 0, 0, 0);
            }
        }

        // ---- cross-wave K-half reduction via LDS ----
        *(f32x4*)&part[w][0][l][0] = aR;
        *(f32x4*)&part[w][1][l][0] = aZ;
        *(f32x4*)&part[w][2][l][0] = aNx;
        *(f32x4*)&part[w][3][l][0] = aNh;
        __syncthreads();

        if (kh == 0) {
            const int pw = w ^ 2;
            const f32x4 pR  = *(const f32x4*)&part[pw][0][l][0];
            const f32x4 pZ  = *(const f32x4*)&part[pw][1][l][0];
            const f32x4 pXn = *(const f32x4*)&part[pw][2][l][0];
            const f32x4 pHn = *(const f32x4*)&part[pw][3][l][0];

            // ---- gates for 4 consecutive cols of batch row l15 ----
            float hnew[4];
#pragma unroll
            for (int i = 0; i < 4; ++i) {
                const float vR  = aR[i]  + pR[i];
                const float vZ  = aZ[i]  + pZ[i];
                const float vXn = aNx[i] + pXn[i];
                const float vHn = aNh[i] + pHn[i];
                const float rr = __builtin_amdgcn_rcpf(1.f + __expf(-vR));
                const float zz = __builtin_amdgcn_rcpf(1.f + __expf(-vZ));
                const float a  = vXn + rr * vHn;
                const float e2 = __expf(2.f * a);
                const float nn = (e2 - 1.f) * __builtin_amdgcn_rcpf(e2 + 1.f);
                hnew[i] = (1.f - zz) * nn + zz * hold[i];
                hold[i] = hnew[i];
            }

            if (t < NS - 1) {
                // ---- publish: ONE packed u64 sc1 store per lane ----
                unsigned long long pk =
                      (unsigned long long)f2bf(hnew[0])
                    | ((unsigned long long)f2bf(hnew[1]) << 16)
                    | ((unsigned long long)f2bf(hnew[2]) << 32)
                    | ((unsigned long long)f2bf(hnew[3]) << 48);
                unsigned long long* dst =
                    (unsigned long long*)(hbuf + (((size_t)wb * 16 + g) * 16 + jb) * 512);
                st_agent_u64(dst + u64idx, pk);
            } else {
                *(f32x4*)&hT[(size_t)(r0 + l15) * NH + cw0 + lq * 4] = *(f32x4*)hnew;
            }
        }

        if (t < NS - 1) {
            // ---- x-proj(t+1) shadows the store drain ----
            float xt[16];
            *(f32x4*)(xt)      = xp0; *(f32x4*)(xt + 4)  = xp1;
            *(f32x4*)(xt + 8)  = xp2; *(f32x4*)(xt + 12) = xp3;
            bf16x8 xf0 = pack8(xt), xf1 = pack8(xt + 8);
            aR = bRv; aZ = bZv; aNx = bNxv; aNh = bNhv;
            aR  = __builtin_amdgcn_mfma_f32_16x16x32_bf16(wih[0][0], xf0, aR, 0, 0, 0);
            aZ  = __builtin_amdgcn_mfma_f32_16x16x32_bf16(wih[1][0], xf0, aZ, 0, 0, 0);
            aNx = __builtin_amdgcn_mfma_f32_16x16x32_bf16(wih[2][0], xf0, aNx, 0, 0, 0);
            aR  = __builtin_amdgcn_mfma_f32_16x16x32_bf16(wih[0][1], xf1, aR, 0, 0, 0);
            aZ  = __builtin_amdgcn_mfma_f32_16x16x32_bf16(wih[1][1], xf1, aZ, 0, 0, 0);
            aNx = __builtin_amdgcn_mfma_f32_16x16x32_bf16(wih[2][1], xf1, aNx, 0, 0, 0);

            asm volatile("s_waitcnt vmcnt(0)" ::: "memory");  // h stores ack'd at IC
            __syncthreads();                                  // all 4 waves drained
            if (tid == 0) st_agent_u32(&fl[jb], (unsigned)(t + 1));

            // ---- prefetch x(t+2) AFTER flag (never blocks the drain) ----
            if (t + 2 < NS) {
                const float* xp = xptr0 + (size_t)(t + 2) * NI;
                xp0 = *(const f32x4*)(xp + 0);
                xp1 = *(const f32x4*)(xp + 4);
                xp2 = *(const f32x4*)(xp + 32);
                xp3 = *(const f32x4*)(xp + 36);
            }
        }
    }
}

// out[256,1000] = hT[256,512] @ W_head^T + b_head, pure fp32.
__global__ void __launch_bounds__(256, 1) gru_head(
    const float* __restrict__ hT,
    const float* __restrict__ Wh,
    const float* __restrict__ bh,
    float* __restrict__ out)
{
    __shared__ float hs[16 * 512];
    const int tid = threadIdx.x;
    const int rg  = blockIdx.x;
    const int cgp = blockIdx.y;
    const float* src = hT + rg * (16 * 512);
#pragma unroll
    for (int i = 0; i < 32; ++i) hs[tid + 256 * i] = src[tid + 256 * i];
    __syncthreads();
    const int col = (cgp << 6) + (tid & 63);
    const int rb  = (tid >> 6) << 2;
    if (col < NC) {
        const float* wr = Wh + col * NH;
        float a0 = 0.f, a1 = 0.f, a2 = 0.f, a3 = 0.f;
        for (int k = 0; k < NH; k += 4) {
            const f32x4 wv = *(const f32x4*)(wr + k);
            const f32x4 h0 = *(const f32x4*)&hs[(rb + 0) * NH + k];
            const f32x4 h1 = *(const f32x4*)&hs[(rb + 1) * NH + k];
            const f32x4 h2 = *(const f32x4*)&hs[(rb + 2) * NH + k];
            const f32x4 h3 = *(const f32x4*)&hs[(rb + 3) * NH + k];
#pragma unroll
            for (int j = 0; j < 4; ++j) {
                a0 = fmaf(wv[j], h0[j], a0);
                a1 = fmaf(wv[j], h1[j], a1);
                a2 = fmaf(wv[j], h2[j], a2);
                a3 = fmaf(wv[j], h3[j], a3);
            }
        }
        const float bb = bh[col];
        const int orow = (rg << 4) + rb;
        out[(orow + 0) * NC + col] = a0 + bb;
        out[(orow + 1) * NC + col] = a1 + bb;
        out[(orow + 2) * NC + col] = a2 + bb;
        out[(orow + 3) * NC + col] = a3 + bb;
    }
}

extern "C" void kernel_launch(void* const* d_in, const int* in_sizes, int n_in,
                              void* d_out, int out_size, void* d_ws, size_t ws_size,
                              hipStream_t stream)
{
    (void)in_sizes; (void)n_in; (void)out_size; (void)ws_size;
    const float* x     = (const float*)d_in[0];
    const float* Wih   = (const float*)d_in[1];
    const float* Whh   = (const float*)d_in[2];
    const float* bih   = (const float*)d_in[3];
    const float* bhh   = (const float*)d_in[4];
    const float* Whead = (const float*)d_in[5];
    const float* bhead = (const float*)d_in[6];
    float* out = (float*)d_out;

    char* ws = (char*)d_ws;
    unsigned short* hbuf  = (unsigned short*)ws;                  // 2*16*16*512*2B = 512KB
    unsigned int*   flags = (unsigned int*)(ws + 512 * 1024);     // 512 u32 = 2KB
    float*          hT    = (float*)(ws + 512 * 1024 + 2048);     // 512KB

    gru_init_ws<<<2, 256, 0, stream>>>(flags);
    gru_scan<<<256, 256, 0, stream>>>(x, Wih, Whh, bih, bhh, hbuf, hT, flags);
    gru_head<<<dim3(16, 16), 256, 0, stream>>>(hT, Whead, bhead, out);
}